// Round 3
// baseline (137.695 us; speedup 1.0000x reference)
//
#include <hip/hip_runtime.h>
#include <math.h>

#define LEAK 0.2f

__device__ __forceinline__ float leaky_f(float x) { return x >= 0.0f ? x : LEAK * x; }
__device__ __forceinline__ float sigmoid_f(float x) { return 1.0f / (1.0f + expf(-x)); }

// Intra-wave LDS fence: orders this wave's LDS writes before subsequent reads.
// Wave-synchronous (64-lane lockstep) stages B-E run entirely in wave 0, so a
// workgroup barrier is not needed -- and waves 1-7 can prefetch concurrently
// without being drained by the vmcnt(0)-before-s_barrier the compiler emits.
__device__ __forceinline__ void wave_lds_fence() {
    __builtin_amdgcn_wave_barrier();
    __threadfence_block();
    __builtin_amdgcn_wave_barrier();
}

// One block per batch element (B=32), 512 threads.
// Only timesteps t=0,1,2 matter: the reference output is out[:, 2:3, :].
// Wave 0: serial small-MLP chain (stages B-E). Waves 1-7: float4 bulk
// prefetch of all large/late weights into L2. They overlap; the single
// __syncthreads joins them before the wide stages (F, LSTM, head).
__global__ __launch_bounds__(512)
void lstm_cls_kernel(const float* __restrict__ data,
                     const float* __restrict__ W_M1, const float* __restrict__ b_M1,
                     const float* __restrict__ W_M2, const float* __restrict__ b_M2,
                     const float* __restrict__ W_T1, const float* __restrict__ b_T1,
                     const float* __restrict__ W_T2, const float* __restrict__ b_T2,
                     const float* __restrict__ W_S1, const float* __restrict__ b_S1,
                     const float* __restrict__ W_S2, const float* __restrict__ b_S2,
                     const float* __restrict__ Wk,   const float* __restrict__ b_l,
                     const float* __restrict__ Wr,
                     const float* __restrict__ W_P1, const float* __restrict__ b_P1,
                     const float* __restrict__ W_P2, const float* __restrict__ b_P2,
                     const float* __restrict__ W_P3, const float* __restrict__ b_P3,
                     const float* __restrict__ W_P4, const float* __restrict__ b_P4,
                     const float* __restrict__ W_P5, const float* __restrict__ b_P5,
                     float* __restrict__ out)
{
    __shared__ float sdata[3][11];   // data[b, t, :] for t=0..2
    __shared__ float feat[3][124];   // lstm_in: [M(16) Tsk(16) Psk(16) Pa(1) S(64) data(11)]
    __shared__ float m1s[3][8];
    __shared__ float t1s[3][8];
    __shared__ float s1s[3][32];
    __shared__ float zx[3][512];
    __shared__ float zs[4][128];
    __shared__ float h[128];
    __shared__ float pp[8][64];      // split-K partials for head layers
    __shared__ float d1[64], d2[32], d3[16], d4[8];
    __shared__ float sm[3];

    const int b   = blockIdx.x;
    const int tid = threadIdx.x;
    const float* db = data + (size_t)b * 4096 * 11;

    float pf = 0.0f;

    if (tid < 64) {
        // ================= wave 0: serial small-MLP chain =================
        // ---- load data[b, 0:3, :] (33 floats) ----
        if (tid < 33) {
            int t = tid / 11, k = tid % 11;
            float v = db[t * 11 + k];
            sdata[t][k] = v;
            feat[t][113 + k] = v;          // lstm_in tail = raw data
        }
        wave_lds_fence();

        // ---- stage B: m1 [24 tasks], t1 [24], Pa [3] ----
        if (tid < 24) {
            int t = tid / 8, j = tid % 8;
            float acc = b_M1[j];
            for (int k = 0; k < 6; ++k) acc += sdata[t][4 + k] * W_M1[k * 8 + j];
            m1s[t][j] = leaky_f(acc);
        } else if (tid < 48) {
            int u = tid - 24, t = u / 8, j = u % 8;
            float acc = b_T1[j];
            for (int k = 0; k < 11; ++k) acc += sdata[t][k] * W_T1[k * 8 + j];
            t1s[t][j] = fabsf(leaky_f(acc));
        } else if (tid < 51) {
            int t = tid - 48;
            feat[t][48] = log1pf(sdata[t][1]);   // Pa = log1p(Ta)
        }
        wave_lds_fence();

        // ---- stage C: M [48], Tsk + Psk [48] ----
        for (int idx = tid; idx < 96; idx += 64) {
            int t, j;
            if (idx < 48) {
                t = idx / 16; j = idx % 16;
                float acc = b_M2[j];
                for (int k = 0; k < 8; ++k) acc += m1s[t][k] * W_M2[k * 16 + j];
                feat[t][j] = leaky_f(acc);                 // M
            } else {
                int u = idx - 48; t = u / 16; j = u % 16;
                float acc = b_T2[j];
                for (int k = 0; k < 8; ++k) acc += t1s[t][k] * W_T2[k * 16 + j];
                float v = fabsf(leaky_f(acc));
                feat[t][16 + j] = v;                       // Tsk
                feat[t][32 + j] = log1pf(v);               // Psk
            }
        }
        wave_lds_fence();

        // ---- stage D: s1 = leaky(s_in @ W_S1 + b), s_in = [feat[0:49] env body] ----
        for (int idx = tid; idx < 96; idx += 64) {
            int t = idx / 32, j = idx % 32;
            float acc = b_S1[j];
            for (int k = 0; k < 49; ++k) acc += feat[t][k] * W_S1[k * 32 + j];
            for (int k = 0; k < 3;  ++k) acc += sdata[t][1 + k] * W_S1[(49 + k) * 32 + j]; // env
            for (int k = 0; k < 6;  ++k) acc += sdata[t][4 + k] * W_S1[(52 + k) * 32 + j]; // body
            s1s[t][j] = leaky_f(acc);
        }
        wave_lds_fence();

        // ---- stage E: S = leaky(s1 @ W_S2 + b) [192 tasks] ----
        for (int idx = tid; idx < 192; idx += 64) {
            int t = idx / 64, j = idx % 64;
            float acc = b_S2[j];
            for (int k = 0; k < 32; ++k) acc += s1s[t][k] * W_S2[k * 64 + j];
            feat[t][49 + j] = leaky_f(acc);
        }
    } else {
        // ============ waves 1-7: float4 bulk prefetch into L2 =============
        const int widx = tid - 64;     // 0..447
        float4 a = make_float4(0.f, 0.f, 0.f, 0.f);
        // late-stage small weights + b_l first (land before wave 0 needs them)
        const float4* p;
        p = (const float4*)b_l;
        for (int i = widx; i < 128;   i += 448) { float4 v = p[i]; a.x+=v.x; a.y+=v.y; a.z+=v.z; a.w+=v.w; }
        p = (const float4*)W_S1;
        for (int i = widx; i < 464;   i += 448) { float4 v = p[i]; a.x+=v.x; a.y+=v.y; a.z+=v.z; a.w+=v.w; }
        p = (const float4*)W_S2;
        for (int i = widx; i < 512;   i += 448) { float4 v = p[i]; a.x+=v.x; a.y+=v.y; a.z+=v.z; a.w+=v.w; }
        p = (const float4*)Wk;         // 124*512 = 63488 floats
        for (int i = widx; i < 15872; i += 448) { float4 v = p[i]; a.x+=v.x; a.y+=v.y; a.z+=v.z; a.w+=v.w; }
        p = (const float4*)Wr;         // 128*512 = 65536 floats
        for (int i = widx; i < 16384; i += 448) { float4 v = p[i]; a.x+=v.x; a.y+=v.y; a.z+=v.z; a.w+=v.w; }
        p = (const float4*)W_P1;       // 8192 floats
        for (int i = widx; i < 2048;  i += 448) { float4 v = p[i]; a.x+=v.x; a.y+=v.y; a.z+=v.z; a.w+=v.w; }
        p = (const float4*)W_P2;       // 2048 floats
        for (int i = widx; i < 512;   i += 448) { float4 v = p[i]; a.x+=v.x; a.y+=v.y; a.z+=v.z; a.w+=v.w; }
        p = (const float4*)W_P3;       // 512 floats
        for (int i = widx; i < 128;   i += 448) { float4 v = p[i]; a.x+=v.x; a.y+=v.y; a.z+=v.z; a.w+=v.w; }
        p = (const float4*)W_P4;       // 128 floats
        for (int i = widx; i < 32;    i += 448) { float4 v = p[i]; a.x+=v.x; a.y+=v.y; a.z+=v.z; a.w+=v.w; }
        p = (const float4*)W_P5;       // 24 floats
        for (int i = widx; i < 6;     i += 448) { float4 v = p[i]; a.x+=v.x; a.y+=v.y; a.z+=v.z; a.w+=v.w; }
        pf = a.x + a.y + a.z + a.w;
    }

    if (tid < 128) h[tid] = 0.0f;
    float c = 0.0f;                    // live only for tid < 128
    const int g = tid >> 7, j = tid & 127;
    __syncthreads();

    // ---- stage F: zx[t][col] for col=tid; one Wk load feeds all 3 timesteps ----
    {
        const int col = tid;
        float a0 = b_l[col], a1 = a0, a2 = a0;
        #pragma unroll 8
        for (int k = 0; k < 124; ++k) {
            float w = Wk[k * 512 + col];
            a0 += feat[0][k] * w;
            a1 += feat[1][k] * w;
            a2 += feat[2][k] * w;
        }
        zx[0][col] = a0; zx[1][col] = a1; zx[2][col] = a2;
    }
    __syncthreads();

    // ---- LSTM: 3 steps, gate-parallel (thread (g,j) computes z[g*128+j]) ----
    for (int t = 0; t < 3; ++t) {
        float z = zx[t][(g << 7) + j];
        if (t > 0) {
            #pragma unroll 8
            for (int k = 0; k < 128; ++k)
                z += h[k] * Wr[k * 512 + (g << 7) + j];   // coalesced: tid-consecutive
        }
        zs[g][j] = z;
        __syncthreads();
        if (g == 0) {
            float zi = zs[0][j], zf = zs[1][j], zg = zs[2][j], zo = zs[3][j];
            c = sigmoid_f(zf) * c + sigmoid_f(zi) * leaky_f(zg);
            h[j] = sigmoid_f(zo) * leaky_f(c);
        }
        __syncthreads();
    }

    // ---- head: 128 -> 64 (split-K 8x16) ----
    {
        int part = tid >> 6, jj = tid & 63;
        float acc = 0.0f;
        for (int k = part * 16; k < part * 16 + 16; ++k)
            acc += h[k] * W_P1[k * 64 + jj];
        pp[part][jj] = acc;
    }
    __syncthreads();
    if (tid < 64) {
        float acc = b_P1[tid];
        for (int p = 0; p < 8; ++p) acc += pp[p][tid];
        d1[tid] = leaky_f(acc);
    }
    __syncthreads();

    // ---- 64 -> 32 (split-K 8x8) ----
    if (tid < 256) {
        int part = tid >> 5, jj = tid & 31;
        float acc = 0.0f;
        for (int k = part * 8; k < part * 8 + 8; ++k)
            acc += d1[k] * W_P2[k * 32 + jj];
        pp[part][jj] = acc;
    }
    __syncthreads();
    if (tid < 32) {
        float acc = b_P2[tid];
        for (int p = 0; p < 8; ++p) acc += pp[p][tid];
        d2[tid] = leaky_f(acc);
    }
    __syncthreads();

    // ---- 32 -> 16 (split-K 8x4) ----
    if (tid < 128) {
        int part = tid >> 4, jj = tid & 15;
        float acc = 0.0f;
        for (int k = part * 4; k < part * 4 + 4; ++k)
            acc += d2[k] * W_P3[k * 16 + jj];
        pp[part][jj] = acc;
    }
    __syncthreads();
    if (tid < 16) {
        float acc = b_P3[tid];
        for (int p = 0; p < 8; ++p) acc += pp[p][tid];
        d3[tid] = leaky_f(acc);
    }
    __syncthreads();

    // ---- 16 -> 8 ----
    if (tid < 8) {
        float acc = b_P4[tid];
        for (int k = 0; k < 16; ++k) acc += d3[k] * W_P4[k * 8 + tid];
        d4[tid] = leaky_f(acc);
    }
    __syncthreads();

    // ---- 8 -> 3 + softmax ----
    if (tid == 0) {
        float l[3], mx = -1e30f;
        for (int r = 0; r < 3; ++r) {
            float acc = b_P5[r];
            for (int k = 0; k < 8; ++k) acc += d4[k] * W_P5[k * 3 + r];
            l[r] = leaky_f(acc);
            mx = fmaxf(mx, l[r]);
        }
        float s = 0.0f;
        for (int r = 0; r < 3; ++r) { l[r] = expf(l[r] - mx); s += l[r]; }
        float inv = 1.0f / s;
        for (int r = 0; r < 3; ++r) sm[r] = l[r] * inv;
    }
    __syncthreads();

    // ---- outputs: d_out[0:96] = softmax(t=2); d_out[96:512] = concat(data[b,2,1:11], softmax) ----
    if (tid < 3)  out[b * 3 + tid] = sm[tid];
    if (tid < 13) {
        float v = (tid < 10) ? sdata[2][1 + tid] : sm[tid - 10];
        out[96 + b * 13 + tid] = v;
    }

    // keep the prefetch accumulator observable so the loads aren't dead-code
    // eliminated; condition is provably-false at runtime (data ~ U[0,1)).
    if (pf == -1234.5678f && sdata[2][0] == -99999.0f) out[0] = pf;
}

extern "C" void kernel_launch(void* const* d_in, const int* in_sizes, int n_in,
                              void* d_out, int out_size, void* d_ws, size_t ws_size,
                              hipStream_t stream) {
    const float* data = (const float*)d_in[0];
    const float* W_M1 = (const float*)d_in[1];
    const float* b_M1 = (const float*)d_in[2];
    const float* W_M2 = (const float*)d_in[3];
    const float* b_M2 = (const float*)d_in[4];
    const float* W_T1 = (const float*)d_in[5];
    const float* b_T1 = (const float*)d_in[6];
    const float* W_T2 = (const float*)d_in[7];
    const float* b_T2 = (const float*)d_in[8];
    const float* W_S1 = (const float*)d_in[9];
    const float* b_S1 = (const float*)d_in[10];
    const float* W_S2 = (const float*)d_in[11];
    const float* b_S2 = (const float*)d_in[12];
    const float* Wk   = (const float*)d_in[13];
    const float* Wr   = (const float*)d_in[14];
    const float* b_l  = (const float*)d_in[15];
    const float* W_P1 = (const float*)d_in[16];
    const float* b_P1 = (const float*)d_in[17];
    const float* W_P2 = (const float*)d_in[18];
    const float* b_P2 = (const float*)d_in[19];
    const float* W_P3 = (const float*)d_in[20];
    const float* b_P3 = (const float*)d_in[21];
    const float* W_P4 = (const float*)d_in[22];
    const float* b_P4 = (const float*)d_in[23];
    const float* W_P5 = (const float*)d_in[24];
    const float* b_P5 = (const float*)d_in[25];
    float* out = (float*)d_out;

    lstm_cls_kernel<<<dim3(32), dim3(512), 0, stream>>>(
        data, W_M1, b_M1, W_M2, b_M2, W_T1, b_T1, W_T2, b_T2,
        W_S1, b_S1, W_S2, b_S2, Wk, b_l, Wr,
        W_P1, b_P1, W_P2, b_P2, W_P3, b_P3, W_P4, b_P4, W_P5, b_P5,
        out);
}

// Round 4
// 123.942 us; speedup vs baseline: 1.1110x; 1.1110x over previous
//
#include <hip/hip_runtime.h>
#include <math.h>

#define LEAK 0.2f

__device__ __forceinline__ float leaky_f(float x) { return x >= 0.0f ? x : LEAK * x; }
__device__ __forceinline__ float sigmoid_f(float x) { return 1.0f / (1.0f + expf(-x)); }

// Small-weight LDS staging offsets (floats). All segment starts %4 == 0 so
// float4 LDS stores are 16B-aligned.
#define OP1 0        // W_P1 128x64 = 8192
#define OP2 8192     // W_P2 64x32 = 2048
#define OP3 10240    // W_P3 32x16 = 512
#define OP4 10752    // W_P4 16x8  = 128
#define OP5 10880    // W_P5 8x3   = 24
#define OB1 10904    // b_P1 64
#define OB2 10968    // b_P2 32
#define OB3 11000    // b_P3 16
#define OB4 11016    // b_P4 8
#define OBL 11024    // b_l  512
#define OB5 11536    // b_P5 3 (padded)
#define WLS_N 11540

// One block per batch element (B=32), 512 threads. Only t=0,1,2 matter
// (reference output is out[:, 2:3, :]).
// Key design: maximize memory-level parallelism per thread.
//  - Wr preloaded into 32 float4 REGISTERS/thread at T=0 (all in flight at
//    once) -> LSTM matvecs do zero global loads.
//  - Stage B/C weight columns + biases preloaded into registers -> pure VALU.
//  - W_P*/b_* staged to LDS via float4 at T=0 -> head does zero global loads.
//  - Stages D/E/F use float4 row loads with split-K so each is 8-31
//    simultaneously-outstanding float4 loads (~1-2 HBM round trips).
__global__ __launch_bounds__(512)
void lstm_cls_kernel(const float* __restrict__ data,
                     const float* __restrict__ W_M1, const float* __restrict__ b_M1,
                     const float* __restrict__ W_M2, const float* __restrict__ b_M2,
                     const float* __restrict__ W_T1, const float* __restrict__ b_T1,
                     const float* __restrict__ W_T2, const float* __restrict__ b_T2,
                     const float* __restrict__ W_S1, const float* __restrict__ b_S1,
                     const float* __restrict__ W_S2, const float* __restrict__ b_S2,
                     const float* __restrict__ Wk,   const float* __restrict__ b_l,
                     const float* __restrict__ Wr,
                     const float* __restrict__ W_P1, const float* __restrict__ b_P1,
                     const float* __restrict__ W_P2, const float* __restrict__ b_P2,
                     const float* __restrict__ W_P3, const float* __restrict__ b_P3,
                     const float* __restrict__ W_P4, const float* __restrict__ b_P4,
                     const float* __restrict__ W_P5, const float* __restrict__ b_P5,
                     float* __restrict__ out)
{
    __shared__ float sdata[3][11];
    __shared__ float feat[3][124];   // [M(16) Tsk(16) Psk(16) Pa(1) S(64) data(11)]
    __shared__ float m1s[3][8];
    __shared__ float t1s[3][8];
    __shared__ float s1s[3][32];
    __shared__ float dpart[8][3][32];   // stage D split-K partials
    __shared__ float epart[4][3][64];   // stage E split-K partials
    __shared__ float zpart[4][3][512];  // stage F partials; LSTM reuses [q][0]
    __shared__ float zx[3][512];
    __shared__ float h[128];
    __shared__ float pp[8][64];
    __shared__ float d1[64], d2[32], d3[16], d4[8], smx[3];
    __shared__ float wls[WLS_N];

    const int b   = blockIdx.x;
    const int tid = threadIdx.x;
    const int q   = tid >> 7;      // 0..3 (k-quarter for F / LSTM split-K)
    const int c4  = tid & 127;     // float4-column group
    const float* db = data + (size_t)b * 4096 * 11;

    // ================= T=0: issue ALL long-latency loads =================
    // data[b, 0:3, :]
    if (tid < 33) {
        int t = tid / 11, k = tid % 11;
        float v = db[t * 11 + k];
        sdata[t][k] = v;
        feat[t][113 + k] = v;
    }

    // Wr -> registers: thread (q,c4) holds rows 32q..32q+31, f4-col c4.
    const float4* Wr4 = (const float4*)Wr;
    float4 rw[32];
    #pragma unroll
    for (int kk = 0; kk < 32; ++kk)
        rw[kk] = Wr4[(32 * q + kk) * 128 + c4];

    // Stage B/C weight columns + biases -> registers (pure-VALU B/C later).
    float wB[11]; float bBv = 0.0f;
    float wC[8];  float bCv = 0.0f;
    float bs1v = 0.0f, bs2v = 0.0f;
    if (tid < 24) {
        int j = tid & 7; bBv = b_M1[j];
        #pragma unroll
        for (int k = 0; k < 6; ++k) wB[k] = W_M1[k * 8 + j];
    } else if (tid < 48) {
        int j = (tid - 24) & 7; bBv = b_T1[j];
        #pragma unroll
        for (int k = 0; k < 11; ++k) wB[k] = W_T1[k * 8 + j];
    }
    if (tid < 48) {
        int j = tid & 15; bCv = b_M2[j];
        #pragma unroll
        for (int k = 0; k < 8; ++k) wC[k] = W_M2[k * 16 + j];
    } else if (tid < 96) {
        int j = (tid - 48) & 15; bCv = b_T2[j];
        #pragma unroll
        for (int k = 0; k < 8; ++k) wC[k] = W_T2[k * 16 + j];
    }
    if (tid < 96)  bs1v = b_S1[tid & 31];
    if (tid < 192) bs2v = b_S2[tid & 63];

    // Small weights / biases -> LDS (float4), threads 192-511.
    if (tid >= 192) {
        int wi = tid - 192;                       // 0..319
        float4* wls4 = (float4*)wls;
        for (int i = wi; i < 2048; i += 320) wls4[OP1/4 + i] = ((const float4*)W_P1)[i];
        for (int i = wi; i < 512;  i += 320) wls4[OP2/4 + i] = ((const float4*)W_P2)[i];
        for (int i = wi; i < 128;  i += 320) wls4[OP3/4 + i] = ((const float4*)W_P3)[i];
        for (int i = wi; i < 32;   i += 320) wls4[OP4/4 + i] = ((const float4*)W_P4)[i];
        for (int i = wi; i < 6;    i += 320) wls4[OP5/4 + i] = ((const float4*)W_P5)[i];
        for (int i = wi; i < 16;   i += 320) wls4[OB1/4 + i] = ((const float4*)b_P1)[i];
        for (int i = wi; i < 8;    i += 320) wls4[OB2/4 + i] = ((const float4*)b_P2)[i];
        for (int i = wi; i < 4;    i += 320) wls4[OB3/4 + i] = ((const float4*)b_P3)[i];
        for (int i = wi; i < 2;    i += 320) wls4[OB4/4 + i] = ((const float4*)b_P4)[i];
        for (int i = wi; i < 128;  i += 320) wls4[OBL/4 + i] = ((const float4*)b_l)[i];
        if (wi < 3) wls[OB5 + wi] = b_P5[wi];
    }
    __syncthreads();   // barrier-1: data visible; preloads drained (~1-2 trips)

    // ---- stage B (register weights, pure VALU) ----
    if (tid < 24) {
        int t = tid / 8, j = tid & 7;
        float acc = bBv;
        #pragma unroll
        for (int k = 0; k < 6; ++k) acc += sdata[t][4 + k] * wB[k];
        m1s[t][j] = leaky_f(acc);
    } else if (tid < 48) {
        int u = tid - 24, t = u / 8, j = u & 7;
        float acc = bBv;
        #pragma unroll
        for (int k = 0; k < 11; ++k) acc += sdata[t][k] * wB[k];
        t1s[t][j] = fabsf(leaky_f(acc));
    } else if (tid < 51) {
        int t = tid - 48;
        feat[t][48] = log1pf(sdata[t][1]);   // Pa
    }
    __syncthreads();

    // ---- stage C (register weights) ----
    if (tid < 48) {
        int t = tid / 16, j = tid & 15;
        float acc = bCv;
        #pragma unroll
        for (int k = 0; k < 8; ++k) acc += m1s[t][k] * wC[k];
        feat[t][j] = leaky_f(acc);                  // M
    } else if (tid < 96) {
        int u = tid - 48, t = u / 16, j = u & 15;
        float acc = bCv;
        #pragma unroll
        for (int k = 0; k < 8; ++k) acc += t1s[t][k] * wC[k];
        float v = fabsf(leaky_f(acc));
        feat[t][16 + j] = v;                        // Tsk
        feat[t][32 + j] = log1pf(v);                // Psk
    }
    __syncthreads();

    // ---- stage D: s1 = leaky(s_in @ W_S1 + b), s_in[58], split-K 8 x f4 ----
    if (tid < 192) {
        int kk = tid & 7, j4 = (tid >> 3) & 7, t = tid >> 6;
        int k0 = kk * 8, k1 = k0 + 8; if (k1 > 58) k1 = 58;
        const float4* WS1_4 = (const float4*)W_S1;
        float4 a = make_float4(0.f, 0.f, 0.f, 0.f);
        for (int k = k0; k < k1; ++k) {
            float4 w = WS1_4[k * 8 + j4];
            float sv = (k < 49) ? feat[t][k] : sdata[t][k - 48];
            a.x = fmaf(sv, w.x, a.x); a.y = fmaf(sv, w.y, a.y);
            a.z = fmaf(sv, w.z, a.z); a.w = fmaf(sv, w.w, a.w);
        }
        ((float4*)&dpart[kk][t][0])[j4] = a;
    }
    __syncthreads();
    if (tid < 96) {
        int t = tid >> 5, j = tid & 31;
        float acc = bs1v;
        #pragma unroll
        for (int kk = 0; kk < 8; ++kk) acc += dpart[kk][t][j];
        s1s[t][j] = leaky_f(acc);
    }
    __syncthreads();

    // ---- stage E: S = leaky(s1 @ W_S2 + b), split-K 4 x f4 ----
    if (tid < 192) {
        int kk = tid & 3, j4 = (tid >> 2) & 15, t = tid >> 6;
        const float4* WS2_4 = (const float4*)W_S2;
        float4 a = make_float4(0.f, 0.f, 0.f, 0.f);
        #pragma unroll
        for (int i = 0; i < 8; ++i) {
            int k = 8 * kk + i;
            float4 w = WS2_4[k * 16 + j4];
            float sv = s1s[t][k];
            a.x = fmaf(sv, w.x, a.x); a.y = fmaf(sv, w.y, a.y);
            a.z = fmaf(sv, w.z, a.z); a.w = fmaf(sv, w.w, a.w);
        }
        ((float4*)&epart[kk][t][0])[j4] = a;
    }
    __syncthreads();
    if (tid < 192) {
        int t = tid >> 6, j = tid & 63;
        float acc = bs2v;
        #pragma unroll
        for (int kk = 0; kk < 4; ++kk) acc += epart[kk][t][j];
        feat[t][49 + j] = leaky_f(acc);
    }
    __syncthreads();

    // ---- stage F: zx = feat @ Wk + b_l, split-K 4 x f4, 3 timesteps ----
    {
        const float4* Wk4 = (const float4*)Wk;
        float4 f0 = make_float4(0.f,0.f,0.f,0.f), f1 = f0, f2 = f0;
        #pragma unroll
        for (int i = 0; i < 31; ++i) {
            int k = 31 * q + i;
            float4 w = Wk4[k * 128 + c4];
            float a = feat[0][k], bb = feat[1][k], cc = feat[2][k];
            f0.x = fmaf(a,  w.x, f0.x); f0.y = fmaf(a,  w.y, f0.y);
            f0.z = fmaf(a,  w.z, f0.z); f0.w = fmaf(a,  w.w, f0.w);
            f1.x = fmaf(bb, w.x, f1.x); f1.y = fmaf(bb, w.y, f1.y);
            f1.z = fmaf(bb, w.z, f1.z); f1.w = fmaf(bb, w.w, f1.w);
            f2.x = fmaf(cc, w.x, f2.x); f2.y = fmaf(cc, w.y, f2.y);
            f2.z = fmaf(cc, w.z, f2.z); f2.w = fmaf(cc, w.w, f2.w);
        }
        ((float4*)&zpart[q][0][0])[c4] = f0;
        ((float4*)&zpart[q][1][0])[c4] = f1;
        ((float4*)&zpart[q][2][0])[c4] = f2;
    }
    __syncthreads();
    #pragma unroll
    for (int t = 0; t < 3; ++t) {
        int col = tid;
        zx[t][col] = wls[OBL + col] + zpart[0][t][col] + zpart[1][t][col]
                   + zpart[2][t][col] + zpart[3][t][col];
    }
    __syncthreads();

    // ---- LSTM: 3 steps; Wr lives in rw[] registers, zero global loads ----
    float c = 0.0f;
    if (tid < 128) {   // t = 0 (h=0, c=0)
        float zi = zx[0][tid], zf = zx[0][128 + tid];
        float zg = zx[0][256 + tid], zo = zx[0][384 + tid];
        (void)zf;
        c = sigmoid_f(zi) * leaky_f(zg);
        h[tid] = sigmoid_f(zo) * leaky_f(c);
    }
    __syncthreads();
    for (int t = 1; t < 3; ++t) {
        float4 acc = make_float4(0.f, 0.f, 0.f, 0.f);
        #pragma unroll
        for (int kk = 0; kk < 32; ++kk) {
            float hk = h[32 * q + kk];     // wave-uniform LDS broadcast
            acc.x = fmaf(hk, rw[kk].x, acc.x);
            acc.y = fmaf(hk, rw[kk].y, acc.y);
            acc.z = fmaf(hk, rw[kk].z, acc.z);
            acc.w = fmaf(hk, rw[kk].w, acc.w);
        }
        ((float4*)&zpart[q][0][0])[c4] = acc;
        __syncthreads();
        if (tid < 128) {
            int j = tid;
            float zi = zx[t][j]       + zpart[0][0][j]       + zpart[1][0][j]       + zpart[2][0][j]       + zpart[3][0][j];
            float zf = zx[t][128 + j] + zpart[0][0][128 + j] + zpart[1][0][128 + j] + zpart[2][0][128 + j] + zpart[3][0][128 + j];
            float zg = zx[t][256 + j] + zpart[0][0][256 + j] + zpart[1][0][256 + j] + zpart[2][0][256 + j] + zpart[3][0][256 + j];
            float zo = zx[t][384 + j] + zpart[0][0][384 + j] + zpart[1][0][384 + j] + zpart[2][0][384 + j] + zpart[3][0][384 + j];
            c = sigmoid_f(zf) * c + sigmoid_f(zi) * leaky_f(zg);
            h[j] = sigmoid_f(zo) * leaky_f(c);
        }
        __syncthreads();
    }

    // ---- head (all weights in LDS wls) ----
    {   // 128 -> 64, split-K 8x16
        int part = tid >> 6, jj = tid & 63;
        float acc = 0.0f;
        #pragma unroll
        for (int i = 0; i < 16; ++i) {
            int k = part * 16 + i;
            acc = fmaf(h[k], wls[OP1 + k * 64 + jj], acc);
        }
        pp[part][jj] = acc;
    }
    __syncthreads();
    if (tid < 64) {
        float acc = wls[OB1 + tid];
        #pragma unroll
        for (int p = 0; p < 8; ++p) acc += pp[p][tid];
        d1[tid] = leaky_f(acc);
    }
    __syncthreads();
    if (tid < 256) {   // 64 -> 32, split-K 8x8
        int part = tid >> 5, jj = tid & 31;
        float acc = 0.0f;
        #pragma unroll
        for (int i = 0; i < 8; ++i) {
            int k = part * 8 + i;
            acc = fmaf(d1[k], wls[OP2 + k * 32 + jj], acc);
        }
        pp[part][jj] = acc;
    }
    __syncthreads();
    if (tid < 32) {
        float acc = wls[OB2 + tid];
        #pragma unroll
        for (int p = 0; p < 8; ++p) acc += pp[p][tid];
        d2[tid] = leaky_f(acc);
    }
    __syncthreads();
    if (tid < 128) {   // 32 -> 16, split-K 8x4
        int part = tid >> 4, jj = tid & 15;
        float acc = 0.0f;
        #pragma unroll
        for (int i = 0; i < 4; ++i) {
            int k = part * 4 + i;
            acc = fmaf(d2[k], wls[OP3 + k * 16 + jj], acc);
        }
        pp[part][jj] = acc;
    }
    __syncthreads();
    if (tid < 16) {
        float acc = wls[OB3 + tid];
        #pragma unroll
        for (int p = 0; p < 8; ++p) acc += pp[p][tid];
        d3[tid] = leaky_f(acc);
    }
    __syncthreads();
    if (tid < 8) {     // 16 -> 8
        float acc = wls[OB4 + tid];
        #pragma unroll
        for (int k = 0; k < 16; ++k) acc = fmaf(d3[k], wls[OP4 + k * 8 + tid], acc);
        d4[tid] = leaky_f(acc);
    }
    __syncthreads();
    if (tid == 0) {    // 8 -> 3 + softmax
        float l[3], mx = -1e30f;
        #pragma unroll
        for (int r = 0; r < 3; ++r) {
            float acc = wls[OB5 + r];
            #pragma unroll
            for (int k = 0; k < 8; ++k) acc = fmaf(d4[k], wls[OP5 + k * 3 + r], acc);
            l[r] = leaky_f(acc);
            mx = fmaxf(mx, l[r]);
        }
        float s = 0.0f;
        #pragma unroll
        for (int r = 0; r < 3; ++r) { l[r] = expf(l[r] - mx); s += l[r]; }
        float inv = 1.0f / s;
        #pragma unroll
        for (int r = 0; r < 3; ++r) smx[r] = l[r] * inv;
    }
    __syncthreads();

    // ---- outputs ----
    if (tid < 3)  out[b * 3 + tid] = smx[tid];
    if (tid < 13) {
        float v = (tid < 10) ? sdata[2][1 + tid] : smx[tid - 10];
        out[96 + b * 13 + tid] = v;
    }
}

extern "C" void kernel_launch(void* const* d_in, const int* in_sizes, int n_in,
                              void* d_out, int out_size, void* d_ws, size_t ws_size,
                              hipStream_t stream) {
    const float* data = (const float*)d_in[0];
    const float* W_M1 = (const float*)d_in[1];
    const float* b_M1 = (const float*)d_in[2];
    const float* W_M2 = (const float*)d_in[3];
    const float* b_M2 = (const float*)d_in[4];
    const float* W_T1 = (const float*)d_in[5];
    const float* b_T1 = (const float*)d_in[6];
    const float* W_T2 = (const float*)d_in[7];
    const float* b_T2 = (const float*)d_in[8];
    const float* W_S1 = (const float*)d_in[9];
    const float* b_S1 = (const float*)d_in[10];
    const float* W_S2 = (const float*)d_in[11];
    const float* b_S2 = (const float*)d_in[12];
    const float* Wk   = (const float*)d_in[13];
    const float* Wr   = (const float*)d_in[14];
    const float* b_l  = (const float*)d_in[15];
    const float* W_P1 = (const float*)d_in[16];
    const float* b_P1 = (const float*)d_in[17];
    const float* W_P2 = (const float*)d_in[18];
    const float* b_P2 = (const float*)d_in[19];
    const float* W_P3 = (const float*)d_in[20];
    const float* b_P3 = (const float*)d_in[21];
    const float* W_P4 = (const float*)d_in[22];
    const float* b_P4 = (const float*)d_in[23];
    const float* W_P5 = (const float*)d_in[24];
    const float* b_P5 = (const float*)d_in[25];
    float* out = (float*)d_out;

    lstm_cls_kernel<<<dim3(32), dim3(512), 0, stream>>>(
        data, W_M1, b_M1, W_M2, b_M2, W_T1, b_T1, W_T2, b_T2,
        W_S1, b_S1, W_S2, b_S2, Wk, b_l, Wr,
        W_P1, b_P1, W_P2, b_P2, W_P3, b_P3, W_P4, b_P4, W_P5, b_P5,
        out);
}